// Round 13
// baseline (1011.769 us; speedup 1.0000x reference)
//
#include <hip/hip_runtime.h>
#include <math.h>

#define NN 50000
#define NE 400000
#define HD 512
#define EDIM 64
#define H2 1024
#define LDT 72           // padded LDS row stride (ushorts) for reg-staged tiles
#define CAP_SLOT 1200000 // padded edge-slot capacity (>= NE + 16*NN worst pad)
#define CAP_TILE 75000   // CAP_SLOT/16
#define CAP_HEAVY 8192   // max multi-tile (deg>16) nodes; expected ~200
#define NBLK_SCAN 98     // ceil(NN/512)

typedef short s16x8 __attribute__((ext_vector_type(8)));
typedef float f32x4 __attribute__((ext_vector_type(4)));

__device__ __forceinline__ unsigned short f2bf(float f) {
    union { float f; unsigned u; } v; v.f = f;
    unsigned r = v.u + 0x7fffu + ((v.u >> 16) & 1u);
    return (unsigned short)(r >> 16);
}
__device__ __forceinline__ float bf2f(unsigned short h) {
    union { unsigned u; float f; } v; v.u = ((unsigned)h) << 16;
    return v.f;
}
__device__ __forceinline__ float silu_f(float t) {
    return t / (1.f + __expf(-t));
}
// async global->LDS, 16B per lane; dest must be linear (base + lane*16)
__device__ __forceinline__ void gload_lds16(const unsigned short* g, unsigned short* l) {
    __builtin_amdgcn_global_load_lds(
        (const __attribute__((address_space(1))) unsigned int*)(g),
        (__attribute__((address_space(3))) unsigned int*)(l), 16, 0, 0);
}

// ---------------- workspace layout (bytes), total ~166.3 MB ----------------
constexpr size_t OFF_AGGRC = 0;                       // f32 [CAP_HEAVY][512] = 16 MB (zeroed)
constexpr size_t OFF_XB   = 16777216;                 // bf16 [NN][512] interleaved = 51.2 MB
constexpr size_t OFF_H1   = 0;                        // bf16 [NN][1024] (aliases aggrc+xb, both dead)
constexpr size_t OFF_H    = 102400000;                // bf16 [NN][512]
constexpr size_t OFF_WET  = 153600000;                // bf16 [512][64]
constexpr size_t OFF_W1T  = OFF_WET + 65536;          // bf16 [1024][512]
constexpr size_t OFF_W2T  = OFF_W1T + 1048576;        // bf16 [512][1024]
constexpr size_t OFF_CNT  = OFF_W2T + 1048576;        // int[50000]   (zeroed)
constexpr size_t OFF_B1S  = OFF_CNT + 200000;         // float[1024]  (zeroed)
constexpr size_t OFF_B1Q  = OFF_B1S + 4096;           // float[1024]  (zeroed)
constexpr size_t OFF_B2S  = OFF_B1Q + 4096;           // float[512]   (zeroed)
constexpr size_t OFF_B2Q  = OFF_B2S + 2048;           // float[512]   (zeroed)
constexpr size_t ZERO_BYTES = 200000 + 4096 + 4096 + 2048 + 2048;
constexpr size_t OFF_TEX  = OFF_B2Q + 2048;           // int[50000]: packed (half_excl<<16)|full_excl -> hid map
constexpr size_t OFF_BSUM = OFF_TEX + 200000;         // int[128]: packed block sums -> half offsets
constexpr size_t OFF_BOFF = OFF_BSUM + 512;           // int[128]: full offsets
constexpr size_t OFF_T    = OFF_BOFF + 512;           // int[16]: [0]=Ftot, [1]=heavy ctr, [2]=total halves
constexpr size_t OFF_CUR  = OFF_T + 64;               // int[50000]
constexpr size_t OFF_NOT  = OFF_CUR + 200000;         // int[75008] node_of_tile (memset 0xFF)
constexpr size_t OFF_SRCP = OFF_NOT + 300032;         // int[CAP_SLOT] (memset 0xFF)
constexpr size_t OFF_EIXP = OFF_SRCP + 4800000;       // int[CAP_SLOT]
constexpr size_t OFF_SC1  = OFF_EIXP + 4800000;       // float[1024]
constexpr size_t OFF_SB1  = OFF_SC1 + 4096;           // float[1024]
constexpr size_t OFF_SC2  = OFF_SB1 + 4096;           // float[512]
constexpr size_t OFF_SB2  = OFF_SC2 + 2048;           // float[512]

// ---------------- weight transpose+convert to bf16 ----------------
__global__ __launch_bounds__(256) void k_convert(const float* __restrict__ We,
    const float* __restrict__ W1, const float* __restrict__ W2,
    unsigned short* __restrict__ wet, unsigned short* __restrict__ w1t,
    unsigned short* __restrict__ w2t) {
    int i = blockIdx.x * 256 + threadIdx.x;
    if (i < 32768) {
        int n = i >> 6, k = i & 63;
        wet[i] = f2bf(We[k * HD + n]);
    } else if (i < 32768 + 524288) {
        int j = i - 32768;
        int n = j >> 9, k = j & 511;
        w1t[j] = f2bf(W1[k * H2 + n]);
    } else if (i < 32768 + 2 * 524288) {
        int j = i - (32768 + 524288);
        int n = j >> 10, k = j & 1023;
        w2t[j] = f2bf(W2[k * HD + n]);
    }
}

// ---------------- x -> bf16, MFMA-gather-interleaved layout ----------------
// xb[n][cb*128 + l*8 + j] = x[n][cb*128 + j*16 + l]
__global__ __launch_bounds__(256) void k_xconv(const float* __restrict__ x,
    unsigned short* __restrict__ xb) {
    int t = blockIdx.x * 256 + threadIdx.x;   // NN*64 threads, 16B out each
    if (t >= NN * 64) return;
    int n = t >> 6, rem = t & 63;
    int cb = rem >> 4, l = rem & 15;
    const float* src = x + (size_t)n * HD + cb * 128 + l;
    unsigned short o[8];
    #pragma unroll
    for (int j = 0; j < 8; ++j) o[j] = f2bf(src[j * 16]);
    *(uint4*)(xb + (size_t)n * HD + cb * 128 + l * 8) = *(const uint4*)o;
}

// ---------------- histogram of dst ----------------
__global__ __launch_bounds__(256) void k_hist(const int* __restrict__ dst, int* __restrict__ counts) {
    int e = blockIdx.x * 256 + threadIdx.x;
    if (e < NE) atomicAdd(&counts[dst[e]], 1);
}

// ---------------- packed dual prefix scan: vfull (low16) + vhalf (high16) ----------------
// field sums per block provably < 2^16 (full <= NE/16+512 = 25512; half <= 512) -> no carry.
__global__ __launch_bounds__(512) void k_scan1(const int* __restrict__ counts,
    int* __restrict__ tile_excl, int* __restrict__ bsum) {
    __shared__ int wsums[8];
    int b = blockIdx.x, t = threadIdx.x;
    int i = b * 512 + t;
    int c = (i < NN) ? counts[i] : 0;
    int v = 0;
    if (c > 8) v = (c + 15) >> 4;           // full tiles for node
    else if (c >= 1) v = 0x10000;           // one half slot
    int lane = t & 63, wid = t >> 6;
    int x = v;
    #pragma unroll
    for (int o = 1; o < 64; o <<= 1) {
        int y = __shfl_up(x, o, 64);
        if (lane >= o) x += y;
    }
    if (lane == 63) wsums[wid] = x;
    __syncthreads();
    if (t == 0) {
        int run = 0;
        for (int w = 0; w < 8; ++w) { int tmp = wsums[w]; wsums[w] = run; run += tmp; }
    }
    __syncthreads();
    int excl = x - v + wsums[wid];          // packed within-block exclusive
    if (i < NN) tile_excl[i] = excl;
    if (t == 511) bsum[b] = excl + v;       // packed block total
}

__global__ void k_scan2(int* __restrict__ bsum, int* __restrict__ boff, int* __restrict__ Tout) {
    if (threadIdx.x == 0) {
        int runf = 0, runh = 0;
        for (int b = 0; b < NBLK_SCAN; ++b) {
            int pk = bsum[b];
            boff[b] = runf;
            bsum[b] = runh;                 // overwrite with half block-offset
            runf += pk & 0xFFFF;
            runh += pk >> 16;
        }
        Tout[0] = runf;   // Ftot (full tiles)
        Tout[1] = 0;      // heavy-node counter (atomic, result-neutral)
        Tout[2] = runh;   // total halves (deterministic)
    }
}

// meta encoding (node_of_tile, pre-memset 0xFFFFFFFF):
//   bits 0-15 idA, bits 16-31 idB
//   idB==0xFFFF: full-reduce, light, write node idA (also lone-half case)
//   idB==0xFFFE: full-reduce, heavy, atomicAdd aggrc[idA=hid]
//   else       : half-pair, rows0-7 -> idA, rows8-15 -> idB
// Half allocation is a pure function of node id (deterministic across replays);
// meta halves written as plain u16 stores (adjacent halves of a word, no atomics).
__global__ __launch_bounds__(512) void k_scan3(const int* __restrict__ counts,
    int* __restrict__ tile_excl, const int* __restrict__ boff, const int* __restrict__ bsum,
    int* __restrict__ cursor, int* __restrict__ node_of_tile, int* __restrict__ Tout) {
    int b = blockIdx.x, t = threadIdx.x;
    int i = b * 512 + t;
    if (i >= NN) return;
    int c = counts[i];
    int pk = tile_excl[i];
    int hid = -1;
    if (c >= 1 && c <= 8) {
        int halfidx = (pk >> 16) + bsum[b];
        int tile = Tout[0] + (halfidx >> 1);
        cursor[i] = tile * 16 + (halfidx & 1) * 8;
        ((unsigned short*)node_of_tile)[tile * 2 + (halfidx & 1)] = (unsigned short)i;
    } else if (c > 8) {
        int tc = (c + 15) >> 4;
        int ts = (pk & 0xFFFF) + boff[b];
        cursor[i] = ts * 16;
        if (c <= 16) {
            node_of_tile[ts] = (int)(0xFFFF0000u | (unsigned)i);
        } else {
            hid = atomicAdd(&Tout[1], 1);
            if (hid >= CAP_HEAVY) hid = CAP_HEAVY - 1;   // never hit in practice
            for (int k = 0; k < tc; ++k)
                node_of_tile[ts + k] = (int)(0xFFFE0000u | (unsigned)hid);
        }
    }
    tile_excl[i] = hid;   // hid map for k_combine_heavy
}

// ---------------- scatter edges into padded (ELL) slots ----------------
__global__ __launch_bounds__(256) void k_scatter(const int* __restrict__ src, const int* __restrict__ dst,
    int* __restrict__ cursor, int* __restrict__ srcp, int* __restrict__ eidxp) {
    int e = blockIdx.x * 256 + threadIdx.x;
    if (e < NE) {
        int d = dst[e];
        int p = atomicAdd(&cursor[d], 1);
        srcp[p] = src[e];
        eidxp[p] = e;
    }
}

// ---------------- fused edge GEMM + reduce + GIN combine; half-tile pairing ----------------
// [R12 known-good] block = 2 tiles x 512 cols, 4 waves (one 128-col block each).
__global__ __launch_bounds__(256, 4) void k_edge(
    const float* __restrict__ ea, const unsigned short* __restrict__ wet,
    const unsigned short* __restrict__ xb, const float* __restrict__ b_e,
    const float* __restrict__ eps,
    const int* __restrict__ srcp, const int* __restrict__ eidxp,
    const int* __restrict__ node_of_tile, const int* __restrict__ Tptr,
    float* __restrict__ aggrc, unsigned short* __restrict__ h) {
    int tile0 = blockIdx.x * 2;
    int T = Tptr[0] + ((Tptr[2] + 1) >> 1);
    if (tile0 >= T) return;
    __shared__ unsigned short As[32 * LDT];   // 4.6 KB
    __shared__ int Ss[32];                    // srcp cache
    __shared__ float Rs[4][256];              // per-wave repack, 4 KB
    int t = threadIdx.x;
    int slot0 = tile0 * 16;
    // stage A: 32 gathered ea rows -> bf16 (zeros for pad slots); 8 threads/row
    {
        int r = t >> 3, qq = t & 7;
        int s = srcp[slot0 + r];
        if (qq == 0) Ss[r] = s;
        unsigned short* lp = As + r * LDT + qq * 8;
        if (s >= 0) {
            int eix = eidxp[slot0 + r];
            const float* gp = ea + (size_t)eix * EDIM + qq * 8;
            float4 v0 = ((const float4*)gp)[0];
            float4 v1 = ((const float4*)gp)[1];
            lp[0] = f2bf(v0.x); lp[1] = f2bf(v0.y); lp[2] = f2bf(v0.z); lp[3] = f2bf(v0.w);
            lp[4] = f2bf(v1.x); lp[5] = f2bf(v1.y); lp[6] = f2bf(v1.z); lp[7] = f2bf(v1.w);
        } else {
            uint4 z = {0u, 0u, 0u, 0u};
            *(uint4*)lp = z;
        }
    }
    __syncthreads();
    int wave = t >> 6, lane = t & 63, l15 = lane & 15, quad = lane >> 4;
    int cblk = wave * 128;
    f32x4 acc[2][8];
    #pragma unroll
    for (int i = 0; i < 2; ++i)
        #pragma unroll
        for (int j = 0; j < 8; ++j) acc[i][j] = (f32x4){0.f, 0.f, 0.f, 0.f};
    #pragma unroll
    for (int k0 = 0; k0 < 64; k0 += 32) {
        s16x8 af[2], bfr[8];
        #pragma unroll
        for (int i = 0; i < 2; ++i)
            af[i] = *(const s16x8*)(As + (i * 16 + l15) * LDT + k0 + quad * 8);
        #pragma unroll
        for (int j = 0; j < 8; ++j)
            bfr[j] = *(const s16x8*)(wet + (size_t)(cblk + j * 16 + l15) * EDIM + k0 + quad * 8);
        #pragma unroll
        for (int i = 0; i < 2; ++i)
            #pragma unroll
            for (int j = 0; j < 8; ++j)
                acc[i][j] = __builtin_amdgcn_mfma_f32_16x16x32_bf16(af[i], bfr[j], acc[i][j], 0, 0, 0);
    }
    float ep = 1.0f + eps[0];
    float bev[8];
    #pragma unroll
    for (int j = 0; j < 8; ++j) bev[j] = b_e[cblk + j * 16 + l15];
    float* rp = Rs[wave];
    #pragma unroll
    for (int i = 0; i < 2; ++i) {
        int tile = tile0 + i;
        unsigned meta = (unsigned)node_of_tile[tile];   // in-bounds; garbage ok if tile>=T
        unsigned idA = meta & 0xFFFFu, idB = meta >> 16;
        bool pair = idB < 0xFFFEu;                      // block-uniform
        int v_own = pair ? (quad < 2 ? (int)idA : (int)idB) : (int)idA;
        int vc = v_own < NN ? v_own : 0;                // clamp for speculative load
        int srow = i * 16 + quad * 4;
        // gather: 4 rows x 16B (one dwordx4 each) + own row, all issued together
        s16x8 xr[4]; float msk[4];
        #pragma unroll
        for (int r = 0; r < 4; ++r) {
            int s = Ss[srow + r];
            msk[r] = s >= 0 ? 1.f : 0.f;
            xr[r] = *(const s16x8*)(xb + (size_t)(s >= 0 ? s : 0) * HD + cblk + l15 * 8);
        }
        s16x8 xo = *(const s16x8*)(xb + (size_t)vc * HD + cblk + l15 * 8);
        float sum8[8];
        #pragma unroll
        for (int j = 0; j < 8; ++j) sum8[j] = 0.f;
        #pragma unroll
        for (int r = 0; r < 4; ++r) {
            #pragma unroll
            for (int j = 0; j < 8; ++j) {
                float vv = acc[i][j][r] + bf2f((unsigned short)xr[r][j]) + bev[j];
                vv = vv > 0.f ? vv : 0.f;
                sum8[j] = fmaf(msk[r], vv, sum8[j]);
            }
        }
        #pragma unroll
        for (int j = 0; j < 8; ++j) sum8[j] += __shfl_xor(sum8[j], 16, 64);
        if (tile < T) {
            if (pair) {
                // half-pair: quads{0,1} hold node A (rows0-7), quads{2,3} node B
                #pragma unroll
                for (int j = 0; j < 8; ++j) {
                    float val = fmaf(ep, bf2f((unsigned short)xo[j]), sum8[j]);
                    if (quad == 0) rp[j * 16 + l15] = val;
                    if (quad == 2) rp[128 + j * 16 + l15] = val;
                }
                // same-wave DS ops complete in order; fence the compiler too
                __builtin_amdgcn_sched_barrier(0);
                int l2 = lane & 31;
                const float* rb_ = rp + (lane >> 5) * 128 + l2 * 4;
                float4 v4 = *(const float4*)rb_;
                uint2 pk;
                pk.x = (unsigned)f2bf(v4.x) | ((unsigned)f2bf(v4.y) << 16);
                pk.y = (unsigned)f2bf(v4.z) | ((unsigned)f2bf(v4.w) << 16);
                *(uint2*)(h + (size_t)v_own * HD + cblk + l2 * 4) = pk;
            } else {
                #pragma unroll
                for (int j = 0; j < 8; ++j) sum8[j] += __shfl_xor(sum8[j], 32, 64);
                if (idB == 0xFFFEu) {
                    if (quad == 0) {
                        float* ap = aggrc + (size_t)idA * HD + cblk;
                        #pragma unroll
                        for (int j = 0; j < 8; ++j) atomicAdd(ap + j * 16 + l15, sum8[j]);
                    }
                } else {
                    // light full tile (or lone half): h = bf16(ep*x_v + sum)
                    int j0 = quad * 2, j1 = j0 + 1;
                    rp[j0 * 16 + l15] = fmaf(ep, bf2f((unsigned short)xo[j0]), sum8[j0]);
                    rp[j1 * 16 + l15] = fmaf(ep, bf2f((unsigned short)xo[j1]), sum8[j1]);
                    __builtin_amdgcn_sched_barrier(0);
                    unsigned pk = (unsigned)f2bf(rp[lane * 2]) |
                                  ((unsigned)f2bf(rp[lane * 2 + 1]) << 16);
                    *(unsigned*)(h + (size_t)idA * HD + cblk + lane * 2) = pk;
                }
            }
        }
    }
}

// ---------------- finish heavy (deg>16) and deg-0 nodes ----------------
__global__ __launch_bounds__(256) void k_combine_heavy(const float* __restrict__ aggrc,
    const float* __restrict__ x, const int* __restrict__ counts, const int* __restrict__ hidmap,
    const float* __restrict__ eps, unsigned short* __restrict__ h) {
    long i = ((long)blockIdx.x * 256 + threadIdx.x) * 4;
    if (i >= (long)NN * HD) return;
    int v = (int)(i >> 9);
    int c = counts[v];
    if (c >= 1 && c <= 16) return;   // done in k_edge
    float ep = 1.0f + eps[0];
    float4 a = {0.f, 0.f, 0.f, 0.f};
    if (c > 16) a = *(const float4*)(aggrc + (size_t)hidmap[v] * HD + (i & (HD - 1)));
    float4 xv = *(const float4*)(x + i);
    uint2 p;
    p.x = (unsigned)f2bf(ep * xv.x + a.x) | ((unsigned)f2bf(ep * xv.y + a.y) << 16);
    p.y = (unsigned)f2bf(ep * xv.z + a.z) | ((unsigned)f2bf(ep * xv.w + a.w) << 16);
    *(uint2*)(h + i) = p;
}

// ---------------- bf16 GEMM + bias + BN stats; BM=64, 2-phase prefetch dbuf ----------------
// Next K-step's stage ISSUED before current compute; ONE __syncthreads per step
// (after compute) -> stage latency overlaps MFMA. LDS 48-52 KB -> still 3 blocks/CU
// (occupancy preserved vs R12, unlike R8's 128-tile dbuf). Staging: gload_lds +
// both-sides XOR swizzle; SILU_A: A async-split (load regs early, silu+ds_write late).
template <bool BF16OUT, bool SILU_A>
__global__ __launch_bounds__(256) void k_gemm_bn(
    const unsigned short* __restrict__ A, const unsigned short* __restrict__ Bt,
    const float* __restrict__ bias, void* __restrict__ Cv,
    float* __restrict__ bn_sum, float* __restrict__ bn_sumsq,
    const float* __restrict__ a_sc, const float* __restrict__ a_sb,
    int M, int K, int Nn) {
    __shared__ unsigned short As[2][SILU_A ? (64 * LDT) : (64 * 64)];  // 18.4 / 16 KB
    __shared__ unsigned short Bs[2][128 * 64];                         // 32 KB
    __shared__ float csum[128], csumsq[128];
    constexpr int LDA = SILU_A ? LDT : 64;
    int nwg = gridDim.x;
    int q = nwg >> 3, r = nwg & 7;
    int xk = blockIdx.x & 7, xj = blockIdx.x >> 3;
    int logical = xk * q + (xk < r ? xk : r) + xj;
    int nnb = Nn >> 7;
    int mblk = logical / nnb, nblk = logical - mblk * nnb;
    int t = threadIdx.x;
    int row0 = mblk * 64, col0 = nblk * 128;
    int wid = t >> 6, lane = t & 63, l15 = lane & 15, quad = lane >> 4;
    int wr = wid >> 1, wc = wid & 1;              // 2x2 wave grid
    int rb = (lane >> 3), cb8 = (lane & 7) * 8;   // gload role: 8 lanes/row, 16B each
    int scb8 = cb8 ^ (rb * 8);                    // pre-swizzled source chunk
    int rswz = (l15 & 7) * 8;                     // read-side XOR (ushorts)
    int rr = t >> 2, qtr = t & 3;                 // SILU_A reg-stage role (16 els/thread)
    int arow = row0 + rr;
    f32x4 acc[2][4];
    #pragma unroll
    for (int i = 0; i < 2; ++i)
        #pragma unroll
        for (int j = 0; j < 4; ++j) acc[i][j] = (f32x4){0.f, 0.f, 0.f, 0.f};

    auto stageB = [&](int buf, int k0) {
        #pragma unroll
        for (int c = 0; c < 4; ++c) {
            int row = (wid * 4 + c) * 8 + rb;
            gload_lds16(Bt + (size_t)(col0 + row) * K + k0 + scb8,
                        Bs[buf] + row * 64 + cb8);
        }
    };
    auto stageA_g = [&](int buf, int k0) {
        #pragma unroll
        for (int c = 0; c < 2; ++c) {
            int row = (wid * 2 + c) * 8 + rb;
            gload_lds16(A + (size_t)(row0 + row) * K + k0 + scb8,
                        As[buf] + row * 64 + cb8);
        }
    };
    auto loadA_regs = [&](int k0, uint4* au) {
        const unsigned short* gp = A + (size_t)arow * K + k0 + qtr * 16;
        #pragma unroll
        for (int jj = 0; jj < 2; ++jj) {
            uint4 z = {0u, 0u, 0u, 0u};
            au[jj] = (arow < M) ? *(const uint4*)(gp + jj * 8) : z;
        }
    };
    auto writeA_silu = [&](int buf, int k0, const uint4* au) {
        int kb = k0 + qtr * 16;
        unsigned short* lp = As[buf] + rr * LDT + qtr * 16;
        #pragma unroll
        for (int jj = 0; jj < 2; ++jj) {
            uint4 u = au[jj];
            float4 sA = *(const float4*)(a_sc + kb + jj * 8);
            float4 sB = *(const float4*)(a_sc + kb + jj * 8 + 4);
            float4 bA = *(const float4*)(a_sb + kb + jj * 8);
            float4 bB = *(const float4*)(a_sb + kb + jj * 8 + 4);
            unsigned short o[8];
            o[0] = f2bf(silu_f(bf2f((unsigned short)(u.x & 0xffffu)) * sA.x + bA.x));
            o[1] = f2bf(silu_f(bf2f((unsigned short)(u.x >> 16)) * sA.y + bA.y));
            o[2] = f2bf(silu_f(bf2f((unsigned short)(u.y & 0xffffu)) * sA.z + bA.z));
            o[3] = f2bf(silu_f(bf2f((unsigned short)(u.y >> 16)) * sA.w + bA.w));
            o[4] = f2bf(silu_f(bf2f((unsigned short)(u.z & 0xffffu)) * sB.x + bB.x));
            o[5] = f2bf(silu_f(bf2f((unsigned short)(u.z >> 16)) * sB.y + bB.y));
            o[6] = f2bf(silu_f(bf2f((unsigned short)(u.w & 0xffffu)) * sB.z + bB.z));
            o[7] = f2bf(silu_f(bf2f((unsigned short)(u.w >> 16)) * sB.w + bB.w));
            #pragma unroll
            for (int m = 0; m < 8; ++m) lp[jj * 8 + m] = o[m];
        }
    };

    // ---- prologue: stage step 0 into buf 0 ----
    stageB(0, 0);
    if constexpr (!SILU_A) {
        stageA_g(0, 0);
    } else {
        uint4 au0[2];
        loadA_regs(0, au0);
        writeA_silu(0, 0, au0);
    }
    __syncthreads();   // drains -> buf0 ready

    int nsteps = K >> 6;
    int cur = 0;
    for (int s = 0; s < nsteps; ++s) {
        bool hn = (s + 1) < nsteps;
        int k0n = (s + 1) << 6;
        uint4 au[2];
        if (hn) {
            stageB(cur ^ 1, k0n);
            if constexpr (!SILU_A) stageA_g(cur ^ 1, k0n);
            else loadA_regs(k0n, au);
        }
        // ---- compute on buf[cur] (prefetch loads in flight) ----
        #pragma unroll
        for (int kk = 0; kk < 64; kk += 32) {
            s16x8 af[2], bfr[4];
            #pragma unroll
            for (int i = 0; i < 2; ++i) {
                if constexpr (SILU_A)
                    af[i] = *(const s16x8*)(As[cur] + (wr * 32 + i * 16 + l15) * LDA + kk + quad * 8);
                else
                    af[i] = *(const s16x8*)(As[cur] + (wr * 32 + i * 16 + l15) * 64 + ((kk + quad * 8) ^ rswz));
            }
            #pragma unroll
            for (int j = 0; j < 4; ++j)
                bfr[j] = *(const s16x8*)(Bs[cur] + (wc * 64 + j * 16 + l15) * 64 + ((kk + quad * 8) ^ rswz));
            #pragma unroll
            for (int i = 0; i < 2; ++i)
                #pragma unroll
                for (int j = 0; j < 4; ++j)
                    acc[i][j] = __builtin_amdgcn_mfma_f32_16x16x32_bf16(af[i], bfr[j], acc[i][j], 0, 0, 0);
        }
        if (hn) {
            if constexpr (SILU_A) writeA_silu(cur ^ 1, k0n, au);  // A loads done during MFMA
        }
        __syncthreads();   // drains gloads + ds_writes + ds_reads; buffers swap safely
        cur ^= 1;
    }

    if (t < 128) { csum[t] = 0.f; csumsq[t] = 0.f; }
    __syncthreads();
    int mrow0 = row0 + wr * 32;
    #pragma unroll
    for (int j = 0; j < 4; ++j) {
        int col = wc * 64 + j * 16 + l15;
        float bv = bias[col0 + col];
        float ls = 0.f, lq = 0.f;
        #pragma unroll
        for (int i = 0; i < 2; ++i) {
            #pragma unroll
            for (int r2 = 0; r2 < 4; ++r2) {
                int row = mrow0 + i * 16 + quad * 4 + r2;
                if (row < M) {
                    float v = acc[i][j][r2] + bv;
                    if (BF16OUT)
                        ((unsigned short*)Cv)[(size_t)row * Nn + col0 + col] = f2bf(v);
                    else
                        ((float*)Cv)[(size_t)row * Nn + col0 + col] = v;
                    ls += v; lq += v * v;
                }
            }
        }
        ls += __shfl_xor(ls, 16, 64); ls += __shfl_xor(ls, 32, 64);
        lq += __shfl_xor(lq, 16, 64); lq += __shfl_xor(lq, 32, 64);
        if (quad == 0) {
            atomicAdd(&csum[col], ls);
            atomicAdd(&csumsq[col], lq);
        }
    }
    __syncthreads();
    if (t < 128) {
        atomicAdd(bn_sum + col0 + t, csum[t]);
        atomicAdd(bn_sumsq + col0 + t, csumsq[t]);
    }
}

// ---------------- BN finalize ----------------
__global__ __launch_bounds__(256) void k_bn_final(const float* __restrict__ s,
    const float* __restrict__ q, const float* __restrict__ g, const float* __restrict__ beta,
    float* __restrict__ scale, float* __restrict__ sbias, int C, float invN) {
    int c = blockIdx.x * 256 + threadIdx.x;
    if (c < C) {
        float mu = s[c] * invN;
        float var = q[c] * invN - mu * mu;
        var = fmaxf(var, 0.f);
        float sc = g[c] * rsqrtf(var + 1e-5f);
        scale[c] = sc;
        sbias[c] = beta[c] - mu * sc;
    }
}

// ---------------- in-place out = silu(out*scale+bias) fp32 ----------------
__global__ __launch_bounds__(256) void k_out(float* __restrict__ out,
    const float* __restrict__ sc, const float* __restrict__ sb, long total) {
    long i = ((long)blockIdx.x * 256 + threadIdx.x) * 4;
    if (i >= total) return;
    int c = (int)(i & (HD - 1));
    float4 v = *(const float4*)(out + i);
    float4 s4 = *(const float4*)(sc + c);
    float4 b4 = *(const float4*)(sb + c);
    float4 o;
    o.x = silu_f(v.x * s4.x + b4.x);
    o.y = silu_f(v.y * s4.y + b4.y);
    o.z = silu_f(v.z * s4.z + b4.z);
    o.w = silu_f(v.w * s4.w + b4.w);
    *(float4*)(out + i) = o;
}

extern "C" void kernel_launch(void* const* d_in, const int* in_sizes, int n_in,
                              void* d_out, int out_size, void* d_ws, size_t ws_size,
                              hipStream_t stream) {
    const float* x      = (const float*)d_in[0];
    const float* ea     = (const float*)d_in[1];
    const int*   ei     = (const int*)d_in[2];     // [2][E]: src then dst
    const float* W_e    = (const float*)d_in[3];
    const float* b_e    = (const float*)d_in[4];
    const float* W1     = (const float*)d_in[5];
    const float* b1     = (const float*)d_in[6];
    const float* g1     = (const float*)d_in[7];
    const float* beta1  = (const float*)d_in[8];
    const float* W2     = (const float*)d_in[9];
    const float* b2     = (const float*)d_in[10];
    const float* g2     = (const float*)d_in[11];
    const float* beta2  = (const float*)d_in[12];
    const float* eps    = (const float*)d_in[13];
    float* out = (float*)d_out;
    char* ws = (char*)d_ws;

    float*          aggrc = (float*)(ws + OFF_AGGRC);
    unsigned short* xb   = (unsigned short*)(ws + OFF_XB);
    unsigned short* h1   = (unsigned short*)(ws + OFF_H1);   // aliases aggrc+xb (dead then)
    unsigned short* h    = (unsigned short*)(ws + OFF_H);
    unsigned short* wet  = (unsigned short*)(ws + OFF_WET);
    unsigned short* w1t  = (unsigned short*)(ws + OFF_W1T);
    unsigned short* w2t  = (unsigned short*)(ws + OFF_W2T);
    int* counts  = (int*)(ws + OFF_CNT);
    float* b1s   = (float*)(ws + OFF_B1S);
    float* b1q   = (float*)(ws + OFF_B1Q);
    float* b2s   = (float*)(ws + OFF_B2S);
    float* b2q   = (float*)(ws + OFF_B2Q);
    int* tex     = (int*)(ws + OFF_TEX);
    int* bsum    = (int*)(ws + OFF_BSUM);
    int* boff    = (int*)(ws + OFF_BOFF);
    int* Tptr    = (int*)(ws + OFF_T);
    int* cursor  = (int*)(ws + OFF_CUR);
    int* notile  = (int*)(ws + OFF_NOT);
    int* srcp    = (int*)(ws + OFF_SRCP);
    int* eidxp   = (int*)(ws + OFF_EIXP);
    float* sc1   = (float*)(ws + OFF_SC1);
    float* sb1   = (float*)(ws + OFF_SB1);
    float* sc2   = (float*)(ws + OFF_SC2);
    float* sb2   = (float*)(ws + OFF_SB2);

    hipMemsetAsync(aggrc, 0, (size_t)CAP_HEAVY * HD * 4, stream);
    hipMemsetAsync(ws + OFF_CNT, 0, ZERO_BYTES, stream);
    hipMemsetAsync(notile, 0xFF, 300032, stream);
    hipMemsetAsync(srcp, 0xFF, (size_t)CAP_SLOT * 4, stream);
    k_convert<<<4224, 256, 0, stream>>>(W_e, W1, W2, wet, w1t, w2t);
    k_xconv<<<(NN * 64 + 255) / 256, 256, 0, stream>>>(x, xb);
    k_hist<<<(NE + 255) / 256, 256, 0, stream>>>(ei + NE, counts);
    k_scan1<<<NBLK_SCAN, 512, 0, stream>>>(counts, tex, bsum);
    k_scan2<<<1, 64, 0, stream>>>(bsum, boff, Tptr);
    k_scan3<<<NBLK_SCAN, 512, 0, stream>>>(counts, tex, boff, bsum, cursor, notile, Tptr);
    k_scatter<<<(NE + 255) / 256, 256, 0, stream>>>(ei, ei + NE, cursor, srcp, eidxp);
    k_edge<<<CAP_TILE / 2, 256, 0, stream>>>(ea, wet, xb, b_e, eps, srcp, eidxp, notile, Tptr, aggrc, h);
    k_combine_heavy<<<(int)(((long)NN * HD / 4 + 255) / 256), 256, 0, stream>>>(
        aggrc, x, counts, tex, eps, h);
    k_gemm_bn<true, false><<<((NN + 63) / 64) * (H2 / 128), 256, 0, stream>>>(
        h, w1t, b1, h1, b1s, b1q, nullptr, nullptr, NN, HD, H2);
    k_bn_final<<<4, 256, 0, stream>>>(b1s, b1q, g1, beta1, sc1, sb1, H2, 1.f / NN);
    k_gemm_bn<false, true><<<((NN + 63) / 64) * (HD / 128), 256, 0, stream>>>(
        h1, w2t, b2, out, b2s, b2q, sc1, sb1, NN, H2, HD);
    k_bn_final<<<2, 256, 0, stream>>>(b2s, b2q, g2, beta2, sc2, sb2, HD, 1.f / NN);
    k_out<<<(int)(((long)NN * HD / 4 + 255) / 256), 256, 0, stream>>>(out, sc2, sb2, (long)NN * HD);
}

// Round 14
// 959.492 us; speedup vs baseline: 1.0545x; 1.0545x over previous
//
#include <hip/hip_runtime.h>
#include <math.h>

#define NN 50000
#define NE 400000
#define HD 512
#define EDIM 64
#define H2 1024
#define LDT 72           // padded LDS row stride (ushorts) for reg-staged 64-col tiles
#define LDT2 136         // padded LDS row stride (ushorts) for reg-staged 128-col tiles
#define CAP_SLOT 1200000 // padded edge-slot capacity (>= NE + 16*NN worst pad)
#define CAP_TILE 75000   // CAP_SLOT/16
#define CAP_HEAVY 8192   // max multi-tile (deg>16) nodes; expected ~200
#define NBLK_SCAN 98     // ceil(NN/512)

typedef short s16x8 __attribute__((ext_vector_type(8)));
typedef float f32x4 __attribute__((ext_vector_type(4)));

__device__ __forceinline__ unsigned short f2bf(float f) {
    union { float f; unsigned u; } v; v.f = f;
    unsigned r = v.u + 0x7fffu + ((v.u >> 16) & 1u);
    return (unsigned short)(r >> 16);
}
__device__ __forceinline__ float bf2f(unsigned short h) {
    union { unsigned u; float f; } v; v.u = ((unsigned)h) << 16;
    return v.f;
}
__device__ __forceinline__ float silu_f(float t) {
    return t / (1.f + __expf(-t));
}
// async global->LDS, 16B per lane; dest must be linear (base + lane*16)
__device__ __forceinline__ void gload_lds16(const unsigned short* g, unsigned short* l) {
    __builtin_amdgcn_global_load_lds(
        (const __attribute__((address_space(1))) unsigned int*)(g),
        (__attribute__((address_space(3))) unsigned int*)(l), 16, 0, 0);
}

// ---------------- workspace layout (bytes), total ~166.3 MB ----------------
constexpr size_t OFF_AGGRC = 0;                       // f32 [CAP_HEAVY][512] = 16 MB (zeroed)
constexpr size_t OFF_XB   = 16777216;                 // bf16 [NN][512] interleaved = 51.2 MB
constexpr size_t OFF_H1   = 0;                        // bf16 [NN][1024] (aliases aggrc+xb, both dead)
constexpr size_t OFF_H    = 102400000;                // bf16 [NN][512]
constexpr size_t OFF_WET  = 153600000;                // bf16 [512][64]
constexpr size_t OFF_W1T  = OFF_WET + 65536;          // bf16 [1024][512]
constexpr size_t OFF_W2T  = OFF_W1T + 1048576;        // bf16 [512][1024]
constexpr size_t OFF_CNT  = OFF_W2T + 1048576;        // int[50000]   (zeroed)
constexpr size_t OFF_B1S  = OFF_CNT + 200000;         // float[1024]  (zeroed)
constexpr size_t OFF_B1Q  = OFF_B1S + 4096;           // float[1024]  (zeroed)
constexpr size_t OFF_B2S  = OFF_B1Q + 4096;           // float[512]   (zeroed)
constexpr size_t OFF_B2Q  = OFF_B2S + 2048;           // float[512]   (zeroed)
constexpr size_t ZERO_BYTES = 200000 + 4096 + 4096 + 2048 + 2048;
constexpr size_t OFF_TEX  = OFF_B2Q + 2048;           // int[50000]: packed (half_excl<<16)|full_excl -> hid map
constexpr size_t OFF_BSUM = OFF_TEX + 200000;         // int[128]: packed block sums -> half offsets
constexpr size_t OFF_BOFF = OFF_BSUM + 512;           // int[128]: full offsets
constexpr size_t OFF_T    = OFF_BOFF + 512;           // int[16]: [0]=Ftot, [1]=heavy ctr, [2]=total halves
constexpr size_t OFF_CUR  = OFF_T + 64;               // int[50000]
constexpr size_t OFF_NOT  = OFF_CUR + 200000;         // int[75008] node_of_tile (memset 0xFF)
constexpr size_t OFF_SRCP = OFF_NOT + 300032;         // int[CAP_SLOT] (memset 0xFF)
constexpr size_t OFF_EIXP = OFF_SRCP + 4800000;       // int[CAP_SLOT]
constexpr size_t OFF_SC1  = OFF_EIXP + 4800000;       // float[1024]
constexpr size_t OFF_SB1  = OFF_SC1 + 4096;           // float[1024]
constexpr size_t OFF_SC2  = OFF_SB1 + 4096;           // float[512]
constexpr size_t OFF_SB2  = OFF_SC2 + 2048;           // float[512]

// ---------------- weight transpose+convert to bf16 ----------------
__global__ __launch_bounds__(256) void k_convert(const float* __restrict__ We,
    const float* __restrict__ W1, const float* __restrict__ W2,
    unsigned short* __restrict__ wet, unsigned short* __restrict__ w1t,
    unsigned short* __restrict__ w2t) {
    int i = blockIdx.x * 256 + threadIdx.x;
    if (i < 32768) {
        int n = i >> 6, k = i & 63;
        wet[i] = f2bf(We[k * HD + n]);
    } else if (i < 32768 + 524288) {
        int j = i - 32768;
        int n = j >> 9, k = j & 511;
        w1t[j] = f2bf(W1[k * H2 + n]);
    } else if (i < 32768 + 2 * 524288) {
        int j = i - (32768 + 524288);
        int n = j >> 10, k = j & 1023;
        w2t[j] = f2bf(W2[k * HD + n]);
    }
}

// ---------------- x -> bf16, MFMA-gather-interleaved layout ----------------
// xb[n][cb*128 + l*8 + j] = x[n][cb*128 + j*16 + l]
__global__ __launch_bounds__(256) void k_xconv(const float* __restrict__ x,
    unsigned short* __restrict__ xb) {
    int t = blockIdx.x * 256 + threadIdx.x;   // NN*64 threads, 16B out each
    if (t >= NN * 64) return;
    int n = t >> 6, rem = t & 63;
    int cb = rem >> 4, l = rem & 15;
    const float* src = x + (size_t)n * HD + cb * 128 + l;
    unsigned short o[8];
    #pragma unroll
    for (int j = 0; j < 8; ++j) o[j] = f2bf(src[j * 16]);
    *(uint4*)(xb + (size_t)n * HD + cb * 128 + l * 8) = *(const uint4*)o;
}

// ---------------- histogram of dst ----------------
__global__ __launch_bounds__(256) void k_hist(const int* __restrict__ dst, int* __restrict__ counts) {
    int e = blockIdx.x * 256 + threadIdx.x;
    if (e < NE) atomicAdd(&counts[dst[e]], 1);
}

// ---------------- packed dual prefix scan: vfull (low16) + vhalf (high16) ----------------
__global__ __launch_bounds__(512) void k_scan1(const int* __restrict__ counts,
    int* __restrict__ tile_excl, int* __restrict__ bsum) {
    __shared__ int wsums[8];
    int b = blockIdx.x, t = threadIdx.x;
    int i = b * 512 + t;
    int c = (i < NN) ? counts[i] : 0;
    int v = 0;
    if (c > 8) v = (c + 15) >> 4;           // full tiles for node
    else if (c >= 1) v = 0x10000;           // one half slot
    int lane = t & 63, wid = t >> 6;
    int x = v;
    #pragma unroll
    for (int o = 1; o < 64; o <<= 1) {
        int y = __shfl_up(x, o, 64);
        if (lane >= o) x += y;
    }
    if (lane == 63) wsums[wid] = x;
    __syncthreads();
    if (t == 0) {
        int run = 0;
        for (int w = 0; w < 8; ++w) { int tmp = wsums[w]; wsums[w] = run; run += tmp; }
    }
    __syncthreads();
    int excl = x - v + wsums[wid];          // packed within-block exclusive
    if (i < NN) tile_excl[i] = excl;
    if (t == 511) bsum[b] = excl + v;       // packed block total
}

__global__ void k_scan2(int* __restrict__ bsum, int* __restrict__ boff, int* __restrict__ Tout) {
    if (threadIdx.x == 0) {
        int runf = 0, runh = 0;
        for (int b = 0; b < NBLK_SCAN; ++b) {
            int pk = bsum[b];
            boff[b] = runf;
            bsum[b] = runh;                 // overwrite with half block-offset
            runf += pk & 0xFFFF;
            runh += pk >> 16;
        }
        Tout[0] = runf;   // Ftot (full tiles)
        Tout[1] = 0;      // heavy-node counter (atomic, result-neutral)
        Tout[2] = runh;   // total halves (deterministic)
    }
}

// meta encoding (node_of_tile, pre-memset 0xFFFFFFFF):
//   idB==0xFFFF: full-reduce light; idB==0xFFFE: heavy; else half-pair (A rows0-7, B rows8-15)
__global__ __launch_bounds__(512) void k_scan3(const int* __restrict__ counts,
    int* __restrict__ tile_excl, const int* __restrict__ boff, const int* __restrict__ bsum,
    int* __restrict__ cursor, int* __restrict__ node_of_tile, int* __restrict__ Tout) {
    int b = blockIdx.x, t = threadIdx.x;
    int i = b * 512 + t;
    if (i >= NN) return;
    int c = counts[i];
    int pk = tile_excl[i];
    int hid = -1;
    if (c >= 1 && c <= 8) {
        int halfidx = (pk >> 16) + bsum[b];
        int tile = Tout[0] + (halfidx >> 1);
        cursor[i] = tile * 16 + (halfidx & 1) * 8;
        ((unsigned short*)node_of_tile)[tile * 2 + (halfidx & 1)] = (unsigned short)i;
    } else if (c > 8) {
        int tc = (c + 15) >> 4;
        int ts = (pk & 0xFFFF) + boff[b];
        cursor[i] = ts * 16;
        if (c <= 16) {
            node_of_tile[ts] = (int)(0xFFFF0000u | (unsigned)i);
        } else {
            hid = atomicAdd(&Tout[1], 1);
            if (hid >= CAP_HEAVY) hid = CAP_HEAVY - 1;   // never hit in practice
            for (int k = 0; k < tc; ++k)
                node_of_tile[ts + k] = (int)(0xFFFE0000u | (unsigned)hid);
        }
    }
    tile_excl[i] = hid;   // hid map for k_combine_heavy
}

// ---------------- scatter edges into padded (ELL) slots ----------------
__global__ __launch_bounds__(256) void k_scatter(const int* __restrict__ src, const int* __restrict__ dst,
    int* __restrict__ cursor, int* __restrict__ srcp, int* __restrict__ eidxp) {
    int e = blockIdx.x * 256 + threadIdx.x;
    if (e < NE) {
        int d = dst[e];
        int p = atomicAdd(&cursor[d], 1);
        srcp[p] = src[e];
        eidxp[p] = e;
    }
}

// ---------------- fused edge GEMM + reduce + GIN combine; half-tile pairing ----------------
// [R12 known-good] block = 2 tiles x 512 cols, 4 waves (one 128-col block each).
__global__ __launch_bounds__(256, 4) void k_edge(
    const float* __restrict__ ea, const unsigned short* __restrict__ wet,
    const unsigned short* __restrict__ xb, const float* __restrict__ b_e,
    const float* __restrict__ eps,
    const int* __restrict__ srcp, const int* __restrict__ eidxp,
    const int* __restrict__ node_of_tile, const int* __restrict__ Tptr,
    float* __restrict__ aggrc, unsigned short* __restrict__ h) {
    int tile0 = blockIdx.x * 2;
    int T = Tptr[0] + ((Tptr[2] + 1) >> 1);
    if (tile0 >= T) return;
    __shared__ unsigned short As[32 * LDT];   // 4.6 KB
    __shared__ int Ss[32];                    // srcp cache
    __shared__ float Rs[4][256];              // per-wave repack, 4 KB
    int t = threadIdx.x;
    int slot0 = tile0 * 16;
    // stage A: 32 gathered ea rows -> bf16 (zeros for pad slots); 8 threads/row
    {
        int r = t >> 3, qq = t & 7;
        int s = srcp[slot0 + r];
        if (qq == 0) Ss[r] = s;
        unsigned short* lp = As + r * LDT + qq * 8;
        if (s >= 0) {
            int eix = eidxp[slot0 + r];
            const float* gp = ea + (size_t)eix * EDIM + qq * 8;
            float4 v0 = ((const float4*)gp)[0];
            float4 v1 = ((const float4*)gp)[1];
            lp[0] = f2bf(v0.x); lp[1] = f2bf(v0.y); lp[2] = f2bf(v0.z); lp[3] = f2bf(v0.w);
            lp[4] = f2bf(v1.x); lp[5] = f2bf(v1.y); lp[6] = f2bf(v1.z); lp[7] = f2bf(v1.w);
        } else {
            uint4 z = {0u, 0u, 0u, 0u};
            *(uint4*)lp = z;
        }
    }
    __syncthreads();
    int wave = t >> 6, lane = t & 63, l15 = lane & 15, quad = lane >> 4;
    int cblk = wave * 128;
    f32x4 acc[2][8];
    #pragma unroll
    for (int i = 0; i < 2; ++i)
        #pragma unroll
        for (int j = 0; j < 8; ++j) acc[i][j] = (f32x4){0.f, 0.f, 0.f, 0.f};
    #pragma unroll
    for (int k0 = 0; k0 < 64; k0 += 32) {
        s16x8 af[2], bfr[8];
        #pragma unroll
        for (int i = 0; i < 2; ++i)
            af[i] = *(const s16x8*)(As + (i * 16 + l15) * LDT + k0 + quad * 8);
        #pragma unroll
        for (int j = 0; j < 8; ++j)
            bfr[j] = *(const s16x8*)(wet + (size_t)(cblk + j * 16 + l15) * EDIM + k0 + quad * 8);
        #pragma unroll
        for (int i = 0; i < 2; ++i)
            #pragma unroll
            for (int j = 0; j < 8; ++j)
                acc[i][j] = __builtin_amdgcn_mfma_f32_16x16x32_bf16(af[i], bfr[j], acc[i][j], 0, 0, 0);
    }
    float ep = 1.0f + eps[0];
    float bev[8];
    #pragma unroll
    for (int j = 0; j < 8; ++j) bev[j] = b_e[cblk + j * 16 + l15];
    float* rp = Rs[wave];
    #pragma unroll
    for (int i = 0; i < 2; ++i) {
        int tile = tile0 + i;
        unsigned meta = (unsigned)node_of_tile[tile];   // in-bounds; garbage ok if tile>=T
        unsigned idA = meta & 0xFFFFu, idB = meta >> 16;
        bool pair = idB < 0xFFFEu;                      // block-uniform
        int v_own = pair ? (quad < 2 ? (int)idA : (int)idB) : (int)idA;
        int vc = v_own < NN ? v_own : 0;                // clamp for speculative load
        int srow = i * 16 + quad * 4;
        // gather: 4 rows x 16B (one dwordx4 each) + own row, all issued together
        s16x8 xr[4]; float msk[4];
        #pragma unroll
        for (int r = 0; r < 4; ++r) {
            int s = Ss[srow + r];
            msk[r] = s >= 0 ? 1.f : 0.f;
            xr[r] = *(const s16x8*)(xb + (size_t)(s >= 0 ? s : 0) * HD + cblk + l15 * 8);
        }
        s16x8 xo = *(const s16x8*)(xb + (size_t)vc * HD + cblk + l15 * 8);
        float sum8[8];
        #pragma unroll
        for (int j = 0; j < 8; ++j) sum8[j] = 0.f;
        #pragma unroll
        for (int r = 0; r < 4; ++r) {
            #pragma unroll
            for (int j = 0; j < 8; ++j) {
                float vv = acc[i][j][r] + bf2f((unsigned short)xr[r][j]) + bev[j];
                vv = vv > 0.f ? vv : 0.f;
                sum8[j] = fmaf(msk[r], vv, sum8[j]);
            }
        }
        #pragma unroll
        for (int j = 0; j < 8; ++j) sum8[j] += __shfl_xor(sum8[j], 16, 64);
        if (tile < T) {
            if (pair) {
                // half-pair: quads{0,1} hold node A (rows0-7), quads{2,3} node B
                #pragma unroll
                for (int j = 0; j < 8; ++j) {
                    float val = fmaf(ep, bf2f((unsigned short)xo[j]), sum8[j]);
                    if (quad == 0) rp[j * 16 + l15] = val;
                    if (quad == 2) rp[128 + j * 16 + l15] = val;
                }
                // same-wave DS ops complete in order; fence the compiler too
                __builtin_amdgcn_sched_barrier(0);
                int l2 = lane & 31;
                const float* rb_ = rp + (lane >> 5) * 128 + l2 * 4;
                float4 v4 = *(const float4*)rb_;
                uint2 pk;
                pk.x = (unsigned)f2bf(v4.x) | ((unsigned)f2bf(v4.y) << 16);
                pk.y = (unsigned)f2bf(v4.z) | ((unsigned)f2bf(v4.w) << 16);
                *(uint2*)(h + (size_t)v_own * HD + cblk + l2 * 4) = pk;
            } else {
                #pragma unroll
                for (int j = 0; j < 8; ++j) sum8[j] += __shfl_xor(sum8[j], 32, 64);
                if (idB == 0xFFFEu) {
                    if (quad == 0) {
                        float* ap = aggrc + (size_t)idA * HD + cblk;
                        #pragma unroll
                        for (int j = 0; j < 8; ++j) atomicAdd(ap + j * 16 + l15, sum8[j]);
                    }
                } else {
                    // light full tile (or lone half): h = bf16(ep*x_v + sum)
                    int j0 = quad * 2, j1 = j0 + 1;
                    rp[j0 * 16 + l15] = fmaf(ep, bf2f((unsigned short)xo[j0]), sum8[j0]);
                    rp[j1 * 16 + l15] = fmaf(ep, bf2f((unsigned short)xo[j1]), sum8[j1]);
                    __builtin_amdgcn_sched_barrier(0);
                    unsigned pk = (unsigned)f2bf(rp[lane * 2]) |
                                  ((unsigned)f2bf(rp[lane * 2 + 1]) << 16);
                    *(unsigned*)(h + (size_t)idA * HD + cblk + lane * 2) = pk;
                }
            }
        }
    }
}

// ---------------- finish heavy (deg>16) and deg-0 nodes ----------------
__global__ __launch_bounds__(256) void k_combine_heavy(const float* __restrict__ aggrc,
    const float* __restrict__ x, const int* __restrict__ counts, const int* __restrict__ hidmap,
    const float* __restrict__ eps, unsigned short* __restrict__ h) {
    long i = ((long)blockIdx.x * 256 + threadIdx.x) * 4;
    if (i >= (long)NN * HD) return;
    int v = (int)(i >> 9);
    int c = counts[v];
    if (c >= 1 && c <= 16) return;   // done in k_edge
    float ep = 1.0f + eps[0];
    float4 a = {0.f, 0.f, 0.f, 0.f};
    if (c > 16) a = *(const float4*)(aggrc + (size_t)hidmap[v] * HD + (i & (HD - 1)));
    float4 xv = *(const float4*)(x + i);
    uint2 p;
    p.x = (unsigned)f2bf(ep * xv.x + a.x) | ((unsigned)f2bf(ep * xv.y + a.y) << 16);
    p.y = (unsigned)f2bf(ep * xv.z + a.z) | ((unsigned)f2bf(ep * xv.w + a.w) << 16);
    *(uint2*)(h + i) = p;
}

// ---------------- bf16 GEMM + bias + BN stats; BM=64, BK=128 single-buffer ----------------
// R12 structure (2 barriers/K-step, gload_lds + both-sides XOR swizzle, XCD swizzle)
// with BK=128: half the K-steps -> barrier/drain cost amortized over 2x work.
// LDS ~50 KB -> still 3 blocks/CU (no occupancy cliff, unlike m132's 128-tile BK=128).
// Row = 16 chunks of 16B; swizzle chunk' = chunk ^ (row&7) (involution per 8-chunk stripe).
template <bool BF16OUT, bool SILU_A>
__global__ __launch_bounds__(256) void k_gemm_bn(
    const unsigned short* __restrict__ A, const unsigned short* __restrict__ Bt,
    const float* __restrict__ bias, void* __restrict__ Cv,
    float* __restrict__ bn_sum, float* __restrict__ bn_sumsq,
    const float* __restrict__ a_sc, const float* __restrict__ a_sb,
    int M, int K, int Nn) {
    __shared__ unsigned short As[SILU_A ? (64 * LDT2) : (64 * 128)];  // 17.4 / 16 KB
    __shared__ unsigned short Bs[128 * 128];                          // 32 KB
    __shared__ float csum[128], csumsq[128];
    constexpr int LDA = SILU_A ? LDT2 : 128;
    int nwg = gridDim.x;
    int q = nwg >> 3, r = nwg & 7;
    int xk = blockIdx.x & 7, xj = blockIdx.x >> 3;
    int logical = xk * q + (xk < r ? xk : r) + xj;
    int nnb = Nn >> 7;
    int mblk = logical / nnb, nblk = logical - mblk * nnb;
    int t = threadIdx.x;
    int row0 = mblk * 64, col0 = nblk * 128;
    int wid = t >> 6, lane = t & 63, l15 = lane & 15, quad = lane >> 4;
    int wr = wid >> 1, wc = wid & 1;              // 2x2 wave grid
    int rb4 = lane >> 4, cb16 = lane & 15;        // gload role: 4 rows/wave, 16 chunks/row
    int rswz = (l15 & 7) * 8;                     // read-side XOR (ushorts)
    int rr = t >> 2, qtr = t & 3;                 // SILU_A reg-stage role (32 els/thread)
    int arow = row0 + rr;
    f32x4 acc[2][4];
    #pragma unroll
    for (int i = 0; i < 2; ++i)
        #pragma unroll
        for (int j = 0; j < 4; ++j) acc[i][j] = (f32x4){0.f, 0.f, 0.f, 0.f};

    for (int k0 = 0; k0 < K; k0 += 128) {
        __syncthreads();
        // ---- B: 32 KB via global_load_lds (8 calls/wave), swizzled source ----
        #pragma unroll
        for (int c = 0; c < 8; ++c) {
            int row = wid * 32 + c * 4 + rb4;
            int scc = (cb16 ^ (row & 7)) * 8;
            gload_lds16(Bt + (size_t)(col0 + row) * K + k0 + scc,
                        Bs + row * 128 + cb16 * 8);
        }
        if constexpr (!SILU_A) {
            // ---- A: 16 KB via global_load_lds (4 calls/wave) ----
            #pragma unroll
            for (int c = 0; c < 4; ++c) {
                int row = wid * 16 + c * 4 + rb4;
                int scc = (cb16 ^ (row & 7)) * 8;
                gload_lds16(A + (size_t)(row0 + row) * K + k0 + scc,
                            As + row * 128 + cb16 * 8);
            }
        } else {
            // ---- A: reg-staged SiLU-BN transform, 32 els/thread ----
            int row = arow;
            int kb = k0 + qtr * 32;
            unsigned short* lp = As + rr * LDT2 + qtr * 32;
            if (row < M) {
                const unsigned short* gp = A + (size_t)row * K + kb;
                #pragma unroll
                for (int jj = 0; jj < 4; ++jj) {
                    uint4 u = *(const uint4*)(gp + jj * 8);
                    float4 sA = *(const float4*)(a_sc + kb + jj * 8);
                    float4 sB = *(const float4*)(a_sc + kb + jj * 8 + 4);
                    float4 bA = *(const float4*)(a_sb + kb + jj * 8);
                    float4 bB = *(const float4*)(a_sb + kb + jj * 8 + 4);
                    unsigned short o[8];
                    o[0] = f2bf(silu_f(bf2f((unsigned short)(u.x & 0xffffu)) * sA.x + bA.x));
                    o[1] = f2bf(silu_f(bf2f((unsigned short)(u.x >> 16)) * sA.y + bA.y));
                    o[2] = f2bf(silu_f(bf2f((unsigned short)(u.y & 0xffffu)) * sA.z + bA.z));
                    o[3] = f2bf(silu_f(bf2f((unsigned short)(u.y >> 16)) * sA.w + bA.w));
                    o[4] = f2bf(silu_f(bf2f((unsigned short)(u.z & 0xffffu)) * sB.x + bB.x));
                    o[5] = f2bf(silu_f(bf2f((unsigned short)(u.z >> 16)) * sB.y + bB.y));
                    o[6] = f2bf(silu_f(bf2f((unsigned short)(u.w & 0xffffu)) * sB.z + bB.z));
                    o[7] = f2bf(silu_f(bf2f((unsigned short)(u.w >> 16)) * sB.w + bB.w));
                    #pragma unroll
                    for (int m = 0; m < 8; ++m) lp[jj * 8 + m] = o[m];
                }
            } else {
                uint4 z = {0u, 0u, 0u, 0u};
                #pragma unroll
                for (int jj = 0; jj < 4; ++jj) *(uint4*)(lp + jj * 8) = z;
            }
        }
        __syncthreads();   // drains vmcnt -> gload_lds data visible
        #pragma unroll
        for (int kk = 0; kk < 128; kk += 32) {
            s16x8 af[2], bfr[4];
            #pragma unroll
            for (int i = 0; i < 2; ++i) {
                if constexpr (SILU_A)
                    af[i] = *(const s16x8*)(As + (wr * 32 + i * 16 + l15) * LDA + kk + quad * 8);
                else
                    af[i] = *(const s16x8*)(As + (wr * 32 + i * 16 + l15) * 128 + ((kk + quad * 8) ^ rswz));
            }
            #pragma unroll
            for (int j = 0; j < 4; ++j)
                bfr[j] = *(const s16x8*)(Bs + (wc * 64 + j * 16 + l15) * 128 + ((kk + quad * 8) ^ rswz));
            #pragma unroll
            for (int i = 0; i < 2; ++i)
                #pragma unroll
                for (int j = 0; j < 4; ++j)
                    acc[i][j] = __builtin_amdgcn_mfma_f32_16x16x32_bf16(af[i], bfr[j], acc[i][j], 0, 0, 0);
        }
    }
    if (t < 128) { csum[t] = 0.f; csumsq[t] = 0.f; }
    __syncthreads();
    int mrow0 = row0 + wr * 32;
    #pragma unroll
    for (int j = 0; j < 4; ++j) {
        int col = wc * 64 + j * 16 + l15;
        float bv = bias[col0 + col];
        float ls = 0.f, lq = 0.f;
        #pragma unroll
        for (int i = 0; i < 2; ++i) {
            #pragma unroll
            for (int r2 = 0; r2 < 4; ++r2) {
                int row = mrow0 + i * 16 + quad * 4 + r2;
                if (row < M) {
                    float v = acc[i][j][r2] + bv;
                    if (BF16OUT)
                        ((unsigned short*)Cv)[(size_t)row * Nn + col0 + col] = f2bf(v);
                    else
                        ((float*)Cv)[(size_t)row * Nn + col0 + col] = v;
                    ls += v; lq += v * v;
                }
            }
        }
        ls += __shfl_xor(ls, 16, 64); ls += __shfl_xor(ls, 32, 64);
        lq += __shfl_xor(lq, 16, 64); lq += __shfl_xor(lq, 32, 64);
        if (quad == 0) {
            atomicAdd(&csum[col], ls);
            atomicAdd(&csumsq[col], lq);
        }
    }
    __syncthreads();
    if (t < 128) {
        atomicAdd(bn_sum + col0 + t, csum[t]);
        atomicAdd(bn_sumsq + col0 + t, csumsq[t]);
    }
}

// ---------------- BN finalize ----------------
__global__ __launch_bounds__(256) void k_bn_final(const float* __restrict__ s,
    const float* __restrict__ q, const float* __restrict__ g, const float* __restrict__ beta,
    float* __restrict__ scale, float* __restrict__ sbias, int C, float invN) {
    int c = blockIdx.x * 256 + threadIdx.x;
    if (c < C) {
        float mu = s[c] * invN;
        float var = q[c] * invN - mu * mu;
        var = fmaxf(var, 0.f);
        float sc = g[c] * rsqrtf(var + 1e-5f);
        scale[c] = sc;
        sbias[c] = beta[c] - mu * sc;
    }
}

// ---------------- in-place out = silu(out*scale+bias) fp32 ----------------
__global__ __launch_bounds__(256) void k_out(float* __restrict__ out,
    const float* __restrict__ sc, const float* __restrict__ sb, long total) {
    long i = ((long)blockIdx.x * 256 + threadIdx.x) * 4;
    if (i >= total) return;
    int c = (int)(i & (HD - 1));
    float4 v = *(const float4*)(out + i);
    float4 s4 = *(const float4*)(sc + c);
    float4 b4 = *(const float4*)(sb + c);
    float4 o;
    o.x = silu_f(v.x * s4.x + b4.x);
    o.y = silu_f(v.y * s4.y + b4.y);
    o.z = silu_f(v.z * s4.z + b4.z);
    o.w = silu_f(v.w * s4.w + b4.w);
    *(float4*)(out + i) = o;
}

extern "C" void kernel_launch(void* const* d_in, const int* in_sizes, int n_in,
                              void* d_out, int out_size, void* d_ws, size_t ws_size,
                              hipStream_t stream) {
    const float* x      = (const float*)d_in[0];
    const float* ea     = (const float*)d_in[1];
    const int*   ei     = (const int*)d_in[2];     // [2][E]: src then dst
    const float* W_e    = (const float*)d_in[3];
    const float* b_e    = (const float*)d_in[4];
    const float* W1     = (const float*)d_in[5];
    const float* b1     = (const float*)d_in[6];
    const float* g1     = (const float*)d_in[7];
    const float* beta1  = (const float*)d_in[8];
    const float* W2     = (const float*)d_in[9];
    const float* b2     = (const float*)d_in[10];
    const float* g2     = (const float*)d_in[11];
    const float* beta2  = (const float*)d_in[12];
    const float* eps    = (const float*)d_in[13];
    float* out = (float*)d_out;
    char* ws = (char*)d_ws;

    float*          aggrc = (float*)(ws + OFF_AGGRC);
    unsigned short* xb   = (unsigned short*)(ws + OFF_XB);
    unsigned short* h1   = (unsigned short*)(ws + OFF_H1);   // aliases aggrc+xb (dead then)
    unsigned short* h    = (unsigned short*)(ws + OFF_H);
    unsigned short* wet  = (unsigned short*)(ws + OFF_WET);
    unsigned short* w1t  = (unsigned short*)(ws + OFF_W1T);
    unsigned short* w2t  = (unsigned short*)(ws + OFF_W2T);
    int* counts  = (int*)(ws + OFF_CNT);
    float* b1s   = (float*)(ws + OFF_B1S);
    float* b1q   = (float*)(ws + OFF_B1Q);
    float* b2s   = (float*)(ws + OFF_B2S);
    float* b2q   = (float*)(ws + OFF_B2Q);
    int* tex     = (int*)(ws + OFF_TEX);
    int* bsum    = (int*)(ws + OFF_BSUM);
    int* boff    = (int*)(ws + OFF_BOFF);
    int* Tptr    = (int*)(ws + OFF_T);
    int* cursor  = (int*)(ws + OFF_CUR);
    int* notile  = (int*)(ws + OFF_NOT);
    int* srcp    = (int*)(ws + OFF_SRCP);
    int* eidxp   = (int*)(ws + OFF_EIXP);
    float* sc1   = (float*)(ws + OFF_SC1);
    float* sb1   = (float*)(ws + OFF_SB1);
    float* sc2   = (float*)(ws + OFF_SC2);
    float* sb2   = (float*)(ws + OFF_SB2);

    hipMemsetAsync(aggrc, 0, (size_t)CAP_HEAVY * HD * 4, stream);
    hipMemsetAsync(ws + OFF_CNT, 0, ZERO_BYTES, stream);
    hipMemsetAsync(notile, 0xFF, 300032, stream);
    hipMemsetAsync(srcp, 0xFF, (size_t)CAP_SLOT * 4, stream);
    k_convert<<<4224, 256, 0, stream>>>(W_e, W1, W2, wet, w1t, w2t);
    k_xconv<<<(NN * 64 + 255) / 256, 256, 0, stream>>>(x, xb);
    k_hist<<<(NE + 255) / 256, 256, 0, stream>>>(ei + NE, counts);
    k_scan1<<<NBLK_SCAN, 512, 0, stream>>>(counts, tex, bsum);
    k_scan2<<<1, 64, 0, stream>>>(bsum, boff, Tptr);
    k_scan3<<<NBLK_SCAN, 512, 0, stream>>>(counts, tex, boff, bsum, cursor, notile, Tptr);
    k_scatter<<<(NE + 255) / 256, 256, 0, stream>>>(ei, ei + NE, cursor, srcp, eidxp);
    k_edge<<<CAP_TILE / 2, 256, 0, stream>>>(ea, wet, xb, b_e, eps, srcp, eidxp, notile, Tptr, aggrc, h);
    k_combine_heavy<<<(int)(((long)NN * HD / 4 + 255) / 256), 256, 0, stream>>>(
        aggrc, x, counts, tex, eps, h);
    k_gemm_bn<true, false><<<((NN + 63) / 64) * (H2 / 128), 256, 0, stream>>>(
        h, w1t, b1, h1, b1s, b1q, nullptr, nullptr, NN, HD, H2);
    k_bn_final<<<4, 256, 0, stream>>>(b1s, b1q, g1, beta1, sc1, sb1, H2, 1.f / NN);
    k_gemm_bn<false, true><<<((NN + 63) / 64) * (HD / 128), 256, 0, stream>>>(
        h1, w2t, b2, out, b2s, b2q, sc1, sb1, NN, H2, HD);
    k_bn_final<<<2, 256, 0, stream>>>(b2s, b2q, g2, beta2, sc2, sb2, HD, 1.f / NN);
    k_out<<<(int)(((long)NN * HD / 4 + 255) / 256), 256, 0, stream>>>(out, sc2, sb2, (long)NN * HD);
}

// Round 15
// 832.419 us; speedup vs baseline: 1.2155x; 1.1527x over previous
//
#include <hip/hip_runtime.h>
#include <math.h>

#define NN 50000
#define NE 400000
#define HD 512
#define EDIM 64
#define H2 1024
#define LDT 72           // padded LDS row stride (ushorts) for reg-staged tiles
#define CAP_SLOT 1200000 // padded edge-slot capacity (>= NE + 16*NN worst pad)
#define CAP_TILE 75000   // CAP_SLOT/16
#define CAP_HEAVY 8192   // max multi-tile (deg>16) nodes; expected ~200
#define NBLK_SCAN 98     // ceil(NN/512)

typedef short s16x8 __attribute__((ext_vector_type(8)));
typedef float f32x4 __attribute__((ext_vector_type(4)));

__device__ __forceinline__ unsigned short f2bf(float f) {
    union { float f; unsigned u; } v; v.f = f;
    unsigned r = v.u + 0x7fffu + ((v.u >> 16) & 1u);
    return (unsigned short)(r >> 16);
}
__device__ __forceinline__ float bf2f(unsigned short h) {
    union { unsigned u; float f; } v; v.u = ((unsigned)h) << 16;
    return v.f;
}
__device__ __forceinline__ float silu_f(float t) {
    return t / (1.f + __expf(-t));
}
// async global->LDS, 16B per lane; dest must be linear (base + lane*16)
__device__ __forceinline__ void gload_lds16(const unsigned short* g, unsigned short* l) {
    __builtin_amdgcn_global_load_lds(
        (const __attribute__((address_space(1))) unsigned int*)(g),
        (__attribute__((address_space(3))) unsigned int*)(l), 16, 0, 0);
}

// ---------------- workspace layout (bytes), total ~166.3 MB ----------------
constexpr size_t OFF_AGGRC = 0;                       // f32 [CAP_HEAVY][512] = 16 MB (zeroed)
constexpr size_t OFF_XB   = 16777216;                 // bf16 [NN][512] interleaved = 51.2 MB
constexpr size_t OFF_H1   = 0;                        // bf16 [NN][1024] (aliases aggrc+xb, both dead)
constexpr size_t OFF_H    = 102400000;                // bf16 [NN][512]
constexpr size_t OFF_WET  = 153600000;                // bf16 [512][64]
constexpr size_t OFF_W1T  = OFF_WET + 65536;          // bf16 [1024][512]
constexpr size_t OFF_W2T  = OFF_W1T + 1048576;        // bf16 [512][1024]
constexpr size_t OFF_CNT  = OFF_W2T + 1048576;        // int[50000]   (zeroed)
constexpr size_t OFF_B1S  = OFF_CNT + 200000;         // float[1024]  (zeroed)
constexpr size_t OFF_B1Q  = OFF_B1S + 4096;           // float[1024]  (zeroed)
constexpr size_t OFF_B2S  = OFF_B1Q + 4096;           // float[512]   (zeroed)
constexpr size_t OFF_B2Q  = OFF_B2S + 2048;           // float[512]   (zeroed)
constexpr size_t ZERO_BYTES = 200000 + 4096 + 4096 + 2048 + 2048;
constexpr size_t OFF_TEX  = OFF_B2Q + 2048;           // int[50000]: packed (half_excl<<16)|full_excl -> hid map
constexpr size_t OFF_BSUM = OFF_TEX + 200000;         // int[128]: packed block sums -> half offsets
constexpr size_t OFF_BOFF = OFF_BSUM + 512;           // int[128]: full offsets
constexpr size_t OFF_T    = OFF_BOFF + 512;           // int[16]: [0]=Ftot, [1]=heavy ctr, [2]=total halves
constexpr size_t OFF_CUR  = OFF_T + 64;               // int[50000]
constexpr size_t OFF_NOT  = OFF_CUR + 200000;         // int[75008] node_of_tile (memset 0xFF)
constexpr size_t OFF_SRCP = OFF_NOT + 300032;         // int[CAP_SLOT] (memset 0xFF)
constexpr size_t OFF_EIXP = OFF_SRCP + 4800000;       // int[CAP_SLOT]
constexpr size_t OFF_SC1  = OFF_EIXP + 4800000;       // float[1024]
constexpr size_t OFF_SB1  = OFF_SC1 + 4096;           // float[1024]
constexpr size_t OFF_SC2  = OFF_SB1 + 4096;           // float[512]
constexpr size_t OFF_SB2  = OFF_SC2 + 2048;           // float[512]

// ---------------- weight transpose+convert to bf16 ----------------
__global__ __launch_bounds__(256) void k_convert(const float* __restrict__ We,
    const float* __restrict__ W1, const float* __restrict__ W2,
    unsigned short* __restrict__ wet, unsigned short* __restrict__ w1t,
    unsigned short* __restrict__ w2t) {
    int i = blockIdx.x * 256 + threadIdx.x;
    if (i < 32768) {
        int n = i >> 6, k = i & 63;
        wet[i] = f2bf(We[k * HD + n]);
    } else if (i < 32768 + 524288) {
        int j = i - 32768;
        int n = j >> 9, k = j & 511;
        w1t[j] = f2bf(W1[k * H2 + n]);
    } else if (i < 32768 + 2 * 524288) {
        int j = i - (32768 + 524288);
        int n = j >> 10, k = j & 1023;
        w2t[j] = f2bf(W2[k * HD + n]);
    }
}

// ---------------- x -> bf16, MFMA-gather-interleaved layout ----------------
// xb[n][cb*128 + l*8 + j] = x[n][cb*128 + j*16 + l]
__global__ __launch_bounds__(256) void k_xconv(const float* __restrict__ x,
    unsigned short* __restrict__ xb) {
    int t = blockIdx.x * 256 + threadIdx.x;   // NN*64 threads, 16B out each
    if (t >= NN * 64) return;
    int n = t >> 6, rem = t & 63;
    int cb = rem >> 4, l = rem & 15;
    const float* src = x + (size_t)n * HD + cb * 128 + l;
    unsigned short o[8];
    #pragma unroll
    for (int j = 0; j < 8; ++j) o[j] = f2bf(src[j * 16]);
    *(uint4*)(xb + (size_t)n * HD + cb * 128 + l * 8) = *(const uint4*)o;
}

// ---------------- histogram of dst ----------------
__global__ __launch_bounds__(256) void k_hist(const int* __restrict__ dst, int* __restrict__ counts) {
    int e = blockIdx.x * 256 + threadIdx.x;
    if (e < NE) atomicAdd(&counts[dst[e]], 1);
}

// ---------------- packed dual prefix scan: vfull (low16) + vhalf (high16) ----------------
__global__ __launch_bounds__(512) void k_scan1(const int* __restrict__ counts,
    int* __restrict__ tile_excl, int* __restrict__ bsum) {
    __shared__ int wsums[8];
    int b = blockIdx.x, t = threadIdx.x;
    int i = b * 512 + t;
    int c = (i < NN) ? counts[i] : 0;
    int v = 0;
    if (c > 8) v = (c + 15) >> 4;           // full tiles for node
    else if (c >= 1) v = 0x10000;           // one half slot
    int lane = t & 63, wid = t >> 6;
    int x = v;
    #pragma unroll
    for (int o = 1; o < 64; o <<= 1) {
        int y = __shfl_up(x, o, 64);
        if (lane >= o) x += y;
    }
    if (lane == 63) wsums[wid] = x;
    __syncthreads();
    if (t == 0) {
        int run = 0;
        for (int w = 0; w < 8; ++w) { int tmp = wsums[w]; wsums[w] = run; run += tmp; }
    }
    __syncthreads();
    int excl = x - v + wsums[wid];          // packed within-block exclusive
    if (i < NN) tile_excl[i] = excl;
    if (t == 511) bsum[b] = excl + v;       // packed block total
}

__global__ void k_scan2(int* __restrict__ bsum, int* __restrict__ boff, int* __restrict__ Tout) {
    if (threadIdx.x == 0) {
        int runf = 0, runh = 0;
        for (int b = 0; b < NBLK_SCAN; ++b) {
            int pk = bsum[b];
            boff[b] = runf;
            bsum[b] = runh;                 // overwrite with half block-offset
            runf += pk & 0xFFFF;
            runh += pk >> 16;
        }
        Tout[0] = runf;   // Ftot (full tiles)
        Tout[1] = 0;      // heavy-node counter (atomic, result-neutral)
        Tout[2] = runh;   // total halves (deterministic)
    }
}

// meta encoding (node_of_tile, pre-memset 0xFFFFFFFF):
//   idB==0xFFFF: full-reduce light; idB==0xFFFE: heavy; else half-pair (A rows0-7, B rows8-15)
__global__ __launch_bounds__(512) void k_scan3(const int* __restrict__ counts,
    int* __restrict__ tile_excl, const int* __restrict__ boff, const int* __restrict__ bsum,
    int* __restrict__ cursor, int* __restrict__ node_of_tile, int* __restrict__ Tout) {
    int b = blockIdx.x, t = threadIdx.x;
    int i = b * 512 + t;
    if (i >= NN) return;
    int c = counts[i];
    int pk = tile_excl[i];
    int hid = -1;
    if (c >= 1 && c <= 8) {
        int halfidx = (pk >> 16) + bsum[b];
        int tile = Tout[0] + (halfidx >> 1);
        cursor[i] = tile * 16 + (halfidx & 1) * 8;
        ((unsigned short*)node_of_tile)[tile * 2 + (halfidx & 1)] = (unsigned short)i;
    } else if (c > 8) {
        int tc = (c + 15) >> 4;
        int ts = (pk & 0xFFFF) + boff[b];
        cursor[i] = ts * 16;
        if (c <= 16) {
            node_of_tile[ts] = (int)(0xFFFF0000u | (unsigned)i);
        } else {
            hid = atomicAdd(&Tout[1], 1);
            if (hid >= CAP_HEAVY) hid = CAP_HEAVY - 1;   // never hit in practice
            for (int k = 0; k < tc; ++k)
                node_of_tile[ts + k] = (int)(0xFFFE0000u | (unsigned)hid);
        }
    }
    tile_excl[i] = hid;   // hid map for k_combine_heavy
}

// ---------------- scatter edges into padded (ELL) slots ----------------
__global__ __launch_bounds__(256) void k_scatter(const int* __restrict__ src, const int* __restrict__ dst,
    int* __restrict__ cursor, int* __restrict__ srcp, int* __restrict__ eidxp) {
    int e = blockIdx.x * 256 + threadIdx.x;
    if (e < NE) {
        int d = dst[e];
        int p = atomicAdd(&cursor[d], 1);
        srcp[p] = src[e];
        eidxp[p] = e;
    }
}

// ---------------- fused edge GEMM + reduce + GIN combine; half-tile pairing ----------------
// [R12 known-good] block = 2 tiles x 512 cols, 4 waves (one 128-col block each).
__global__ __launch_bounds__(256, 4) void k_edge(
    const float* __restrict__ ea, const unsigned short* __restrict__ wet,
    const unsigned short* __restrict__ xb, const float* __restrict__ b_e,
    const float* __restrict__ eps,
    const int* __restrict__ srcp, const int* __restrict__ eidxp,
    const int* __restrict__ node_of_tile, const int* __restrict__ Tptr,
    float* __restrict__ aggrc, unsigned short* __restrict__ h) {
    int tile0 = blockIdx.x * 2;
    int T = Tptr[0] + ((Tptr[2] + 1) >> 1);
    if (tile0 >= T) return;
    __shared__ unsigned short As[32 * LDT];   // 4.6 KB
    __shared__ int Ss[32];                    // srcp cache
    __shared__ float Rs[4][256];              // per-wave repack, 4 KB
    int t = threadIdx.x;
    int slot0 = tile0 * 16;
    // stage A: 32 gathered ea rows -> bf16 (zeros for pad slots); 8 threads/row
    {
        int r = t >> 3, qq = t & 7;
        int s = srcp[slot0 + r];
        if (qq == 0) Ss[r] = s;
        unsigned short* lp = As + r * LDT + qq * 8;
        if (s >= 0) {
            int eix = eidxp[slot0 + r];
            const float* gp = ea + (size_t)eix * EDIM + qq * 8;
            float4 v0 = ((const float4*)gp)[0];
            float4 v1 = ((const float4*)gp)[1];
            lp[0] = f2bf(v0.x); lp[1] = f2bf(v0.y); lp[2] = f2bf(v0.z); lp[3] = f2bf(v0.w);
            lp[4] = f2bf(v1.x); lp[5] = f2bf(v1.y); lp[6] = f2bf(v1.z); lp[7] = f2bf(v1.w);
        } else {
            uint4 z = {0u, 0u, 0u, 0u};
            *(uint4*)lp = z;
        }
    }
    __syncthreads();
    int wave = t >> 6, lane = t & 63, l15 = lane & 15, quad = lane >> 4;
    int cblk = wave * 128;
    f32x4 acc[2][8];
    #pragma unroll
    for (int i = 0; i < 2; ++i)
        #pragma unroll
        for (int j = 0; j < 8; ++j) acc[i][j] = (f32x4){0.f, 0.f, 0.f, 0.f};
    #pragma unroll
    for (int k0 = 0; k0 < 64; k0 += 32) {
        s16x8 af[2], bfr[8];
        #pragma unroll
        for (int i = 0; i < 2; ++i)
            af[i] = *(const s16x8*)(As + (i * 16 + l15) * LDT + k0 + quad * 8);
        #pragma unroll
        for (int j = 0; j < 8; ++j)
            bfr[j] = *(const s16x8*)(wet + (size_t)(cblk + j * 16 + l15) * EDIM + k0 + quad * 8);
        #pragma unroll
        for (int i = 0; i < 2; ++i)
            #pragma unroll
            for (int j = 0; j < 8; ++j)
                acc[i][j] = __builtin_amdgcn_mfma_f32_16x16x32_bf16(af[i], bfr[j], acc[i][j], 0, 0, 0);
    }
    float ep = 1.0f + eps[0];
    float bev[8];
    #pragma unroll
    for (int j = 0; j < 8; ++j) bev[j] = b_e[cblk + j * 16 + l15];
    float* rp = Rs[wave];
    #pragma unroll
    for (int i = 0; i < 2; ++i) {
        int tile = tile0 + i;
        unsigned meta = (unsigned)node_of_tile[tile];   // in-bounds; garbage ok if tile>=T
        unsigned idA = meta & 0xFFFFu, idB = meta >> 16;
        bool pair = idB < 0xFFFEu;                      // block-uniform
        int v_own = pair ? (quad < 2 ? (int)idA : (int)idB) : (int)idA;
        int vc = v_own < NN ? v_own : 0;                // clamp for speculative load
        int srow = i * 16 + quad * 4;
        // gather: 4 rows x 16B (one dwordx4 each) + own row, all issued together
        s16x8 xr[4]; float msk[4];
        #pragma unroll
        for (int r = 0; r < 4; ++r) {
            int s = Ss[srow + r];
            msk[r] = s >= 0 ? 1.f : 0.f;
            xr[r] = *(const s16x8*)(xb + (size_t)(s >= 0 ? s : 0) * HD + cblk + l15 * 8);
        }
        s16x8 xo = *(const s16x8*)(xb + (size_t)vc * HD + cblk + l15 * 8);
        float sum8[8];
        #pragma unroll
        for (int j = 0; j < 8; ++j) sum8[j] = 0.f;
        #pragma unroll
        for (int r = 0; r < 4; ++r) {
            #pragma unroll
            for (int j = 0; j < 8; ++j) {
                float vv = acc[i][j][r] + bf2f((unsigned short)xr[r][j]) + bev[j];
                vv = vv > 0.f ? vv : 0.f;
                sum8[j] = fmaf(msk[r], vv, sum8[j]);
            }
        }
        #pragma unroll
        for (int j = 0; j < 8; ++j) sum8[j] += __shfl_xor(sum8[j], 16, 64);
        if (tile < T) {
            if (pair) {
                // half-pair: quads{0,1} hold node A (rows0-7), quads{2,3} node B
                #pragma unroll
                for (int j = 0; j < 8; ++j) {
                    float val = fmaf(ep, bf2f((unsigned short)xo[j]), sum8[j]);
                    if (quad == 0) rp[j * 16 + l15] = val;
                    if (quad == 2) rp[128 + j * 16 + l15] = val;
                }
                // same-wave DS ops complete in order; fence the compiler too
                __builtin_amdgcn_sched_barrier(0);
                int l2 = lane & 31;
                const float* rb_ = rp + (lane >> 5) * 128 + l2 * 4;
                float4 v4 = *(const float4*)rb_;
                uint2 pk;
                pk.x = (unsigned)f2bf(v4.x) | ((unsigned)f2bf(v4.y) << 16);
                pk.y = (unsigned)f2bf(v4.z) | ((unsigned)f2bf(v4.w) << 16);
                *(uint2*)(h + (size_t)v_own * HD + cblk + l2 * 4) = pk;
            } else {
                #pragma unroll
                for (int j = 0; j < 8; ++j) sum8[j] += __shfl_xor(sum8[j], 32, 64);
                if (idB == 0xFFFEu) {
                    if (quad == 0) {
                        float* ap = aggrc + (size_t)idA * HD + cblk;
                        #pragma unroll
                        for (int j = 0; j < 8; ++j) atomicAdd(ap + j * 16 + l15, sum8[j]);
                    }
                } else {
                    // light full tile (or lone half): h = bf16(ep*x_v + sum)
                    int j0 = quad * 2, j1 = j0 + 1;
                    rp[j0 * 16 + l15] = fmaf(ep, bf2f((unsigned short)xo[j0]), sum8[j0]);
                    rp[j1 * 16 + l15] = fmaf(ep, bf2f((unsigned short)xo[j1]), sum8[j1]);
                    __builtin_amdgcn_sched_barrier(0);
                    unsigned pk = (unsigned)f2bf(rp[lane * 2]) |
                                  ((unsigned)f2bf(rp[lane * 2 + 1]) << 16);
                    *(unsigned*)(h + (size_t)idA * HD + cblk + lane * 2) = pk;
                }
            }
        }
    }
}

// ---------------- finish heavy (deg>16) and deg-0 nodes ----------------
__global__ __launch_bounds__(256) void k_combine_heavy(const float* __restrict__ aggrc,
    const float* __restrict__ x, const int* __restrict__ counts, const int* __restrict__ hidmap,
    const float* __restrict__ eps, unsigned short* __restrict__ h) {
    long i = ((long)blockIdx.x * 256 + threadIdx.x) * 4;
    if (i >= (long)NN * HD) return;
    int v = (int)(i >> 9);
    int c = counts[v];
    if (c >= 1 && c <= 16) return;   // done in k_edge
    float ep = 1.0f + eps[0];
    float4 a = {0.f, 0.f, 0.f, 0.f};
    if (c > 16) a = *(const float4*)(aggrc + (size_t)hidmap[v] * HD + (i & (HD - 1)));
    float4 xv = *(const float4*)(x + i);
    uint2 p;
    p.x = (unsigned)f2bf(ep * xv.x + a.x) | ((unsigned)f2bf(ep * xv.y + a.y) << 16);
    p.y = (unsigned)f2bf(ep * xv.z + a.z) | ((unsigned)f2bf(ep * xv.w + a.w) << 16);
    *(uint2*)(h + i) = p;
}

// ---------------- bf16 GEMM + bias + BN column stats; BM=64 high-occupancy tiles ----------------
// [R12 known-good] Tile 64x128, 4 waves 2x2, acc[2][4]; gload_lds + both-sides XOR
// swizzle; SILU_A reg-staged @ LDT; 1D grid + bijective XCD-chunk swizzle.
template <bool BF16OUT, bool SILU_A>
__global__ __launch_bounds__(256) void k_gemm_bn(
    const unsigned short* __restrict__ A, const unsigned short* __restrict__ Bt,
    const float* __restrict__ bias, void* __restrict__ Cv,
    float* __restrict__ bn_sum, float* __restrict__ bn_sumsq,
    const float* __restrict__ a_sc, const float* __restrict__ a_sb,
    int M, int K, int Nn) {
    __shared__ unsigned short As[SILU_A ? (64 * LDT) : (64 * 64)];   // 9.2 / 8 KB
    __shared__ unsigned short Bs[128 * 64];                          // 16 KB
    __shared__ float csum[128], csumsq[128];
    constexpr int LDA = SILU_A ? LDT : 64;
    int nwg = gridDim.x;
    int q = nwg >> 3, r = nwg & 7;
    int xk = blockIdx.x & 7, xj = blockIdx.x >> 3;
    int logical = xk * q + (xk < r ? xk : r) + xj;
    int nnb = Nn >> 7;
    int mblk = logical / nnb, nblk = logical - mblk * nnb;
    int t = threadIdx.x;
    int row0 = mblk * 64, col0 = nblk * 128;
    int wid = t >> 6, lane = t & 63, l15 = lane & 15, quad = lane >> 4;
    int wr = wid >> 1, wc = wid & 1;              // 2x2 wave grid
    int rb = (lane >> 3), cb8 = (lane & 7) * 8;   // gload role: 8 lanes/row, 16B each
    int scb8 = cb8 ^ (rb * 8);                    // pre-swizzled source chunk
    int rswz = (l15 & 7) * 8;                     // read-side XOR (ushorts)
    f32x4 acc[2][4];
    #pragma unroll
    for (int i = 0; i < 2; ++i)
        #pragma unroll
        for (int j = 0; j < 4; ++j) acc[i][j] = (f32x4){0.f, 0.f, 0.f, 0.f};

    for (int k0 = 0; k0 < K; k0 += 64) {
        __syncthreads();
        #pragma unroll
        for (int c = 0; c < 4; ++c) {
            int row = (wid * 4 + c) * 8 + rb;
            gload_lds16(Bt + (size_t)(col0 + row) * K + k0 + scb8,
                        Bs + row * 64 + cb8);
        }
        if constexpr (!SILU_A) {
            #pragma unroll
            for (int c = 0; c < 2; ++c) {
                int row = (wid * 2 + c) * 8 + rb;
                gload_lds16(A + (size_t)(row0 + row) * K + k0 + scb8,
                            As + row * 64 + cb8);
            }
        } else {
            int rr = t >> 2, qtr = t & 3;
            int row = row0 + rr;
            int kb = k0 + qtr * 16;
            unsigned short* lp = As + rr * LDT + qtr * 16;
            if (row < M) {
                const unsigned short* gp = A + (size_t)row * K + kb;
                #pragma unroll
                for (int jj = 0; jj < 2; ++jj) {
                    uint4 u = *(const uint4*)(gp + jj * 8);
                    float4 sA = *(const float4*)(a_sc + kb + jj * 8);
                    float4 sB = *(const float4*)(a_sc + kb + jj * 8 + 4);
                    float4 bA = *(const float4*)(a_sb + kb + jj * 8);
                    float4 bB = *(const float4*)(a_sb + kb + jj * 8 + 4);
                    unsigned short o[8];
                    o[0] = f2bf(silu_f(bf2f((unsigned short)(u.x & 0xffffu)) * sA.x + bA.x));
                    o[1] = f2bf(silu_f(bf2f((unsigned short)(u.x >> 16)) * sA.y + bA.y));
                    o[2] = f2bf(silu_f(bf2f((unsigned short)(u.y & 0xffffu)) * sA.z + bA.z));
                    o[3] = f2bf(silu_f(bf2f((unsigned short)(u.y >> 16)) * sA.w + bA.w));
                    o[4] = f2bf(silu_f(bf2f((unsigned short)(u.z & 0xffffu)) * sB.x + bB.x));
                    o[5] = f2bf(silu_f(bf2f((unsigned short)(u.z >> 16)) * sB.y + bB.y));
                    o[6] = f2bf(silu_f(bf2f((unsigned short)(u.w & 0xffffu)) * sB.z + bB.z));
                    o[7] = f2bf(silu_f(bf2f((unsigned short)(u.w >> 16)) * sB.w + bB.w));
                    #pragma unroll
                    for (int m = 0; m < 8; ++m) lp[jj * 8 + m] = o[m];
                }
            } else {
                uint4 z = {0u, 0u, 0u, 0u};
                *(uint4*)(lp) = z;
                *(uint4*)(lp + 8) = z;
            }
        }
        __syncthreads();   // drains vmcnt -> gload_lds data visible
        #pragma unroll
        for (int kk = 0; kk < 64; kk += 32) {
            s16x8 af[2], bfr[4];
            #pragma unroll
            for (int i = 0; i < 2; ++i) {
                if constexpr (SILU_A)
                    af[i] = *(const s16x8*)(As + (wr * 32 + i * 16 + l15) * LDA + kk + quad * 8);
                else
                    af[i] = *(const s16x8*)(As + (wr * 32 + i * 16 + l15) * 64 + ((kk + quad * 8) ^ rswz));
            }
            #pragma unroll
            for (int j = 0; j < 4; ++j)
                bfr[j] = *(const s16x8*)(Bs + (wc * 64 + j * 16 + l15) * 64 + ((kk + quad * 8) ^ rswz));
            #pragma unroll
            for (int i = 0; i < 2; ++i)
                #pragma unroll
                for (int j = 0; j < 4; ++j)
                    acc[i][j] = __builtin_amdgcn_mfma_f32_16x16x32_bf16(af[i], bfr[j], acc[i][j], 0, 0, 0);
        }
    }
    if (t < 128) { csum[t] = 0.f; csumsq[t] = 0.f; }
    __syncthreads();
    int mrow0 = row0 + wr * 32;
    #pragma unroll
    for (int j = 0; j < 4; ++j) {
        int col = wc * 64 + j * 16 + l15;
        float bv = bias[col0 + col];
        float ls = 0.f, lq = 0.f;
        #pragma unroll
        for (int i = 0; i < 2; ++i) {
            #pragma unroll
            for (int r2 = 0; r2 < 4; ++r2) {
                int row = mrow0 + i * 16 + quad * 4 + r2;
                if (row < M) {
                    float v = acc[i][j][r2] + bv;
                    if (BF16OUT)
                        ((unsigned short*)Cv)[(size_t)row * Nn + col0 + col] = f2bf(v);
                    else
                        ((float*)Cv)[(size_t)row * Nn + col0 + col] = v;
                    ls += v; lq += v * v;
                }
            }
        }
        ls += __shfl_xor(ls, 16, 64); ls += __shfl_xor(ls, 32, 64);
        lq += __shfl_xor(lq, 16, 64); lq += __shfl_xor(lq, 32, 64);
        if (quad == 0) {
            atomicAdd(&csum[col], ls);
            atomicAdd(&csumsq[col], lq);
        }
    }
    __syncthreads();
    if (t < 128) {
        atomicAdd(bn_sum + col0 + t, csum[t]);
        atomicAdd(bn_sumsq + col0 + t, csumsq[t]);
    }
}

// ---------------- BN finalize ----------------
__global__ __launch_bounds__(256) void k_bn_final(const float* __restrict__ s,
    const float* __restrict__ q, const float* __restrict__ g, const float* __restrict__ beta,
    float* __restrict__ scale, float* __restrict__ sbias, int C, float invN) {
    int c = blockIdx.x * 256 + threadIdx.x;
    if (c < C) {
        float mu = s[c] * invN;
        float var = q[c] * invN - mu * mu;
        var = fmaxf(var, 0.f);
        float sc = g[c] * rsqrtf(var + 1e-5f);
        scale[c] = sc;
        sbias[c] = beta[c] - mu * sc;
    }
}

// ---------------- in-place out = silu(out*scale+bias) fp32 ----------------
__global__ __launch_bounds__(256) void k_out(float* __restrict__ out,
    const float* __restrict__ sc, const float* __restrict__ sb, long total) {
    long i = ((long)blockIdx.x * 256 + threadIdx.x) * 4;
    if (i >= total) return;
    int c = (int)(i & (HD - 1));
    float4 v = *(const float4*)(out + i);
    float4 s4 = *(const float4*)(sc + c);
    float4 b4 = *(const float4*)(sb + c);
    float4 o;
    o.x = silu_f(v.x * s4.x + b4.x);
    o.y = silu_f(v.y * s4.y + b4.y);
    o.z = silu_f(v.z * s4.z + b4.z);
    o.w = silu_f(v.w * s4.w + b4.w);
    *(float4*)(out + i) = o;
}

extern "C" void kernel_launch(void* const* d_in, const int* in_sizes, int n_in,
                              void* d_out, int out_size, void* d_ws, size_t ws_size,
                              hipStream_t stream) {
    const float* x      = (const float*)d_in[0];
    const float* ea     = (const float*)d_in[1];
    const int*   ei     = (const int*)d_in[2];     // [2][E]: src then dst
    const float* W_e    = (const float*)d_in[3];
    const float* b_e    = (const float*)d_in[4];
    const float* W1     = (const float*)d_in[5];
    const float* b1     = (const float*)d_in[6];
    const float* g1     = (const float*)d_in[7];
    const float* beta1  = (const float*)d_in[8];
    const float* W2     = (const float*)d_in[9];
    const float* b2     = (const float*)d_in[10];
    const float* g2     = (const float*)d_in[11];
    const float* beta2  = (const float*)d_in[12];
    const float* eps    = (const float*)d_in[13];
    float* out = (float*)d_out;
    char* ws = (char*)d_ws;

    float*          aggrc = (float*)(ws + OFF_AGGRC);
    unsigned short* xb   = (unsigned short*)(ws + OFF_XB);
    unsigned short* h1   = (unsigned short*)(ws + OFF_H1);   // aliases aggrc+xb (dead then)
    unsigned short* h    = (unsigned short*)(ws + OFF_H);
    unsigned short* wet  = (unsigned short*)(ws + OFF_WET);
    unsigned short* w1t  = (unsigned short*)(ws + OFF_W1T);
    unsigned short* w2t  = (unsigned short*)(ws + OFF_W2T);
    int* counts  = (int*)(ws + OFF_CNT);
    float* b1s   = (float*)(ws + OFF_B1S);
    float* b1q   = (float*)(ws + OFF_B1Q);
    float* b2s   = (float*)(ws + OFF_B2S);
    float* b2q   = (float*)(ws + OFF_B2Q);
    int* tex     = (int*)(ws + OFF_TEX);
    int* bsum    = (int*)(ws + OFF_BSUM);
    int* boff    = (int*)(ws + OFF_BOFF);
    int* Tptr    = (int*)(ws + OFF_T);
    int* cursor  = (int*)(ws + OFF_CUR);
    int* notile  = (int*)(ws + OFF_NOT);
    int* srcp    = (int*)(ws + OFF_SRCP);
    int* eidxp   = (int*)(ws + OFF_EIXP);
    float* sc1   = (float*)(ws + OFF_SC1);
    float* sb1   = (float*)(ws + OFF_SB1);
    float* sc2   = (float*)(ws + OFF_SC2);
    float* sb2   = (float*)(ws + OFF_SB2);

    hipMemsetAsync(aggrc, 0, (size_t)CAP_HEAVY * HD * 4, stream);
    hipMemsetAsync(ws + OFF_CNT, 0, ZERO_BYTES, stream);
    hipMemsetAsync(notile, 0xFF, 300032, stream);
    hipMemsetAsync(srcp, 0xFF, (size_t)CAP_SLOT * 4, stream);
    k_convert<<<4224, 256, 0, stream>>>(W_e, W1, W2, wet, w1t, w2t);
    k_xconv<<<(NN * 64 + 255) / 256, 256, 0, stream>>>(x, xb);
    k_hist<<<(NE + 255) / 256, 256, 0, stream>>>(ei + NE, counts);
    k_scan1<<<NBLK_SCAN, 512, 0, stream>>>(counts, tex, bsum);
    k_scan2<<<1, 64, 0, stream>>>(bsum, boff, Tptr);
    k_scan3<<<NBLK_SCAN, 512, 0, stream>>>(counts, tex, boff, bsum, cursor, notile, Tptr);
    k_scatter<<<(NE + 255) / 256, 256, 0, stream>>>(ei, ei + NE, cursor, srcp, eidxp);
    k_edge<<<CAP_TILE / 2, 256, 0, stream>>>(ea, wet, xb, b_e, eps, srcp, eidxp, notile, Tptr, aggrc, h);
    k_combine_heavy<<<(int)(((long)NN * HD / 4 + 255) / 256), 256, 0, stream>>>(
        aggrc, x, counts, tex, eps, h);
    k_gemm_bn<true, false><<<((NN + 63) / 64) * (H2 / 128), 256, 0, stream>>>(
        h, w1t, b1, h1, b1s, b1q, nullptr, nullptr, NN, HD, H2);
    k_bn_final<<<4, 256, 0, stream>>>(b1s, b1q, g1, beta1, sc1, sb1, H2, 1.f / NN);
    k_gemm_bn<false, true><<<((NN + 63) / 64) * (HD / 128), 256, 0, stream>>>(
        h1, w2t, b2, out, b2s, b2q, sc1, sb1, NN, H2, HD);
    k_bn_final<<<2, 256, 0, stream>>>(b2s, b2q, g2, beta2, sc2, sb2, HD, 1.f / NN);
    k_out<<<(int)(((long)NN * HD / 4 + 255) / 256), 256, 0, stream>>>(out, sc2, sb2, (long)NN * HD);
}